// Round 11
// baseline (269.798 us; speedup 1.0000x reference)
//
#include <hip/hip_runtime.h>
#include <stdint.h>

#define N_NODES 100000
#define CH 128
#define K_NEIGH 16
#define TN 32          // k_gather node tile: 100000/32 = 3125 exact
#define XS_STRIDE 68   // legacy kernel only
#define PS 132         // pivot stride (node-major [n][o])

#define PSWZ(n, o) ((n) * PS + ((o) ^ ((((n) >> 3) & 3) << 3)))

// ============================================================================
// Round 19. r10: k_gather visible (88us, 51% HBM, VALU 15.7%); k_dual ~140us
// (by subtraction), still counter-invisible. r9 showed the ONLY unperturbed
// staging component is the 8-deep global load chain (compiler sinks loads --
// proven r3/r5/r8). Changes:
//  * k_dual: staging split into {8 loads -> v[8]} then {convert+write}: one
//    amortized wait instead of 8 serial round-trips. ks-loop unroll 2.
//  * k_gather: 16 lanes/node, dwordx4 gather loads (256B row per 16-lane
//    group): half the load instrs at same bytes. <=64 VGPR for 8 blk/CU.
//  * single k_wcvt2 launch for both weight matrices.
// ============================================================================

typedef short bf8v __attribute__((ext_vector_type(8)));   // 8 bf16 = 4 VGPR
typedef float f32x4 __attribute__((ext_vector_type(4)));

__device__ __forceinline__ uint32_t pack_bf16x2(float a, float b) {
    union { float f; uint32_t u; } ua, ub;
    ua.f = a; ub.f = b;
    const uint32_t ra = (ua.u + 0x7fffu + ((ua.u >> 16) & 1u)) >> 16;
    const uint32_t rb = (ub.u + 0x7fffu + ((ub.u >> 16) & 1u)) >> 16;
    return ra | (rb << 16);
}
__device__ __forceinline__ uint16_t bf16_rne(float f) {
    union { float f; uint32_t u; } c; c.f = f;
    return (uint16_t)((c.u + 0x7fffu + ((c.u >> 16) & 1u)) >> 16);
}
__device__ __forceinline__ float bf16_tof(uint16_t h) {
    union { uint32_t u; float f; } c; c.u = ((uint32_t)h) << 16; return c.f;
}
__device__ __forceinline__ float bf16_lo(uint32_t u) {
    union { uint32_t u; float f; } c; c.u = u << 16; return c.f;
}
__device__ __forceinline__ float bf16_hi(uint32_t u) {
    union { uint32_t u; float f; } c; c.u = u & 0xffff0000u; return c.f;
}

// ---------------------------------------------------------------------------
// Pre-kernel: W1 and W2 -> (hi, lo) bf16 planes in ONE launch (128 blocks).
// ---------------------------------------------------------------------------
__global__ void k_wcvt2(const float* __restrict__ W1, const float* __restrict__ W2,
                        uint16_t* __restrict__ W1h, uint16_t* __restrict__ W1l,
                        uint16_t* __restrict__ W2h, uint16_t* __restrict__ W2l) {
    const int i = blockIdx.x * 256 + threadIdx.x;
    if (i < CH * CH) {
        const float f = W1[i];
        const uint16_t h = bf16_rne(f);
        W1h[i] = h;
        W1l[i] = bf16_rne(f - bf16_tof(h));
    } else if (i < 2 * CH * CH) {
        const int j = i - CH * CH;
        const float f = W2[j];
        const uint16_t h = bf16_rne(f);
        W2h[j] = h;
        W2l[j] = bf16_rne(f - bf16_tof(h));
    }
}

// ---------------------------------------------------------------------------
// Kernel 1: k_dual. 64-node tile, 4 waves; wave w owns o in [32w, 32w+32).
//   Out[o][n] = D1 + B1[o] + B2[o],  D1 = (W1h+W1l)@Xh + W1h@Xl
//   Yt[n][o]  = bf16(D2),            D2 = (W2h+W2l)@Xh
// Staging: loads hoisted 8-deep, then convert+write (r10 lesson).
// ---------------------------------------------------------------------------
__global__ __launch_bounds__(256, 2) void k_dual(
    const float*    __restrict__ X,    // [C][N] f32
    const uint16_t* __restrict__ W1h,
    const uint16_t* __restrict__ W1l,
    const uint16_t* __restrict__ W2h,
    const uint16_t* __restrict__ W2l,
    const float*    __restrict__ B1,
    const float*    __restrict__ B2,
    uint16_t*       __restrict__ Yt,   // [N][CH] bf16
    float*          __restrict__ Out)  // [O][N] f32
{
    __shared__ __align__(16) uint16_t XsH[64 * 128];  // 16 KB
    __shared__ __align__(16) uint16_t XsL[64 * 128];  // 16 KB

    const int t  = threadIdx.x;
    const int n0 = blockIdx.x * 64;
    const int V  = (N_NODES - n0 < 64) ? (N_NODES - n0) : 64;

    // ---- staging phase A: issue all 8 global loads (static v[8]) ----
    float4 v[8];
#pragma unroll
    for (int it = 0; it < 8; ++it) {
        const int idx = t + it * 256;          // 0..2047
        const int nq = idx & 15, c = idx >> 4;
        v[it] = make_float4(0.f, 0.f, 0.f, 0.f);
        if (nq * 4 < V)
            v[it] = *(const float4*)&X[(size_t)c * N_NODES + n0 + nq * 4];
    }
    // ---- staging phase B: convert hi/lo + transposed swizzled writes ----
#pragma unroll
    for (int it = 0; it < 8; ++it) {
        const int idx = t + it * 256;
        const int nq = idx & 15, c = idx >> 4;
        const float vv0 = v[it].x, vv1 = v[it].y, vv2 = v[it].z, vv3 = v[it].w;
#pragma unroll
        for (int s = 0; s < 4; ++s) {
            const float f = (s == 0) ? vv0 : (s == 1) ? vv1 : (s == 2) ? vv2 : vv3;
            const int n = nq * 4 + s;
            const int byi = (n << 8) + (((c * 2)) ^ ((n & 7) << 4));
            const uint16_t h = bf16_rne(f);
            XsH[byi >> 1] = h;
            XsL[byi >> 1] = bf16_rne(f - bf16_tof(h));
        }
    }
    __syncthreads();

    const int l = t & 63;
    const int w = t >> 6;                 // wave id 0..3
    const int ar = l & 15;                // A row within 16-tile
    const int ac = (l >> 4) * 8;          // A k-offset

    f32x4 d1[2][4], d2[2][4];
#pragma unroll
    for (int ot = 0; ot < 2; ++ot)
#pragma unroll
        for (int nt = 0; nt < 4; ++nt) {
            d1[ot][nt] = (f32x4){0.f, 0.f, 0.f, 0.f};
            d2[ot][nt] = (f32x4){0.f, 0.f, 0.f, 0.f};
        }

#pragma unroll 2
    for (int ks = 0; ks < 4; ++ks) {
        // W-frags for this ks only: 8 x 16B loads, 32 VGPR live
        bf8v a1h[2], a1l[2], a2h[2], a2l[2];
#pragma unroll
        for (int ot = 0; ot < 2; ++ot) {
            const size_t off = (size_t)(w * 32 + ot * 16 + ar) * CH + ks * 32 + ac;
            a1h[ot] = *(const bf8v*)&W1h[off];
            a1l[ot] = *(const bf8v*)&W1l[off];
            a2h[ot] = *(const bf8v*)&W2h[off];
            a2l[ot] = *(const bf8v*)&W2l[off];
        }
#pragma unroll
        for (int nt = 0; nt < 4; ++nt) {
            const int n  = nt * 16 + (l & 15);
            const int byi = (n << 8) + ((ks * 64 + ((l >> 4) * 16)) ^ ((n & 7) << 4));
            const bf8v bh = *(const bf8v*)((const char*)XsH + byi);
            const bf8v bl = *(const bf8v*)((const char*)XsL + byi);
#pragma unroll
            for (int ot = 0; ot < 2; ++ot) {
                d1[ot][nt] = __builtin_amdgcn_mfma_f32_16x16x32_bf16(
                    a1h[ot], bh, d1[ot][nt], 0, 0, 0);
                d1[ot][nt] = __builtin_amdgcn_mfma_f32_16x16x32_bf16(
                    a1l[ot], bh, d1[ot][nt], 0, 0, 0);
                d1[ot][nt] = __builtin_amdgcn_mfma_f32_16x16x32_bf16(
                    a1h[ot], bl, d1[ot][nt], 0, 0, 0);
                d2[ot][nt] = __builtin_amdgcn_mfma_f32_16x16x32_bf16(
                    a2h[ot], bh, d2[ot][nt], 0, 0, 0);
                d2[ot][nt] = __builtin_amdgcn_mfma_f32_16x16x32_bf16(
                    a2l[ot], bh, d2[ot][nt], 0, 0, 0);
            }
        }
    }

    // ---- Out stores: D1 + biases ----
#pragma unroll
    for (int ot = 0; ot < 2; ++ot) {
        const int ob = w * 32 + ot * 16 + (l >> 4) * 4;
        const float b0 = B1[ob + 0] + B2[ob + 0];
        const float b1 = B1[ob + 1] + B2[ob + 1];
        const float b2 = B1[ob + 2] + B2[ob + 2];
        const float b3 = B1[ob + 3] + B2[ob + 3];
#pragma unroll
        for (int nt = 0; nt < 4; ++nt) {
            const int n = nt * 16 + (l & 15);
            if (n < V) {
                float* op = Out + (size_t)ob * N_NODES + n0 + n;
                op[0]                   = d1[ot][nt][0] + b0;
                op[(size_t)N_NODES]     = d1[ot][nt][1] + b1;
                op[(size_t)N_NODES * 2] = d1[ot][nt][2] + b2;
                op[(size_t)N_NODES * 3] = d1[ot][nt][3] + b3;
            }
        }
    }

    // ---- Yt stores: bf16(D2), 8B per (ot,nt) ----
#pragma unroll
    for (int ot = 0; ot < 2; ++ot)
#pragma unroll
        for (int nt = 0; nt < 4; ++nt) {
            const int n = nt * 16 + (l & 15);
            if (n < V) {
                const int o4 = w * 32 + ot * 16 + (l >> 4) * 4;
                uint2 pv;
                pv.x = pack_bf16x2(d2[ot][nt][0], d2[ot][nt][1]);
                pv.y = pack_bf16x2(d2[ot][nt][2], d2[ot][nt][3]);
                *(uint2*)&Yt[(size_t)(n0 + n) * CH + o4] = pv;
            }
        }
}

// ---------------------------------------------------------------------------
// Kernel 2: k_gather. Out[o][n] += mean_k bf16(Yt)[adj[n][k]][o].
// 16 lanes per node, dwordx4 gather loads (full 256B row per group).
// 32-node tiles, 19KB LDS, 8 blocks/CU.
// ---------------------------------------------------------------------------
__global__ __launch_bounds__(256, 8) void k_gather(
    const int*      __restrict__ adj,  // [N][K] int32
    const uint16_t* __restrict__ Yt,   // [N][CH] bf16
    float*          __restrict__ Out)  // [O][N] f32
{
    __shared__ __align__(16) float P[TN * PS];        // 16.9 KB
    __shared__ __align__(16) int adjS[TN * K_NEIGH];  // 2 KB

    const int t  = threadIdx.x;
    const int n0 = blockIdx.x * TN;   // exact tiles

    if (t < 128)
        *(int4*)&adjS[t * 4] = *(const int4*)&adj[(size_t)n0 * K_NEIGH + t * 4];
    __syncthreads();

    // ---- gather-mean: 16 groups of 16 lanes; lane owns 8 channels (16B) ----
    {
        const int q = t & 15;          // channel block: ch = 8q..8q+7
        const int g = t >> 4;          // group -> node within round
#pragma unroll
        for (int r = 0; r < 2; ++r) {
            const int n = r * 16 + g;
            int js[K_NEIGH];
#pragma unroll
            for (int k = 0; k < K_NEIGH; ++k) js[k] = adjS[n * K_NEIGH + k];
            float c0[8], c1[8];
#pragma unroll
            for (int j = 0; j < 8; ++j) { c0[j] = 0.f; c1[j] = 0.f; }
#pragma unroll
            for (int k = 0; k < K_NEIGH; k += 2) {
                const uint4 A = *(const uint4*)&Yt[(size_t)js[k]     * CH + q * 8];
                const uint4 B = *(const uint4*)&Yt[(size_t)js[k + 1] * CH + q * 8];
                c0[0] += bf16_lo(A.x); c0[1] += bf16_hi(A.x);
                c0[2] += bf16_lo(A.y); c0[3] += bf16_hi(A.y);
                c0[4] += bf16_lo(A.z); c0[5] += bf16_hi(A.z);
                c0[6] += bf16_lo(A.w); c0[7] += bf16_hi(A.w);
                c1[0] += bf16_lo(B.x); c1[1] += bf16_hi(B.x);
                c1[2] += bf16_lo(B.y); c1[3] += bf16_hi(B.y);
                c1[4] += bf16_lo(B.z); c1[5] += bf16_hi(B.z);
                c1[6] += bf16_lo(B.w); c1[7] += bf16_hi(B.w);
            }
            float4 s0, s1;
            s0.x = (c0[0] + c1[0]) * 0.0625f;
            s0.y = (c0[1] + c1[1]) * 0.0625f;
            s0.z = (c0[2] + c1[2]) * 0.0625f;
            s0.w = (c0[3] + c1[3]) * 0.0625f;
            s1.x = (c0[4] + c1[4]) * 0.0625f;
            s1.y = (c0[5] + c1[5]) * 0.0625f;
            s1.z = (c0[6] + c1[6]) * 0.0625f;
            s1.w = (c0[7] + c1[7]) * 0.0625f;
            // PSWZ XOR flips o bits 3..4 only -> 4-aligned float4 runs stay
            // contiguous; q*8 and q*8+4 each map to aligned float4 slots.
            *(float4*)&P[PSWZ(n, q * 8)]     = s0;
            *(float4*)&P[PSWZ(n, q * 8 + 4)] = s1;
        }
    }
    __syncthreads();

    // ---- RMW epilogue: Out[o][n0..n0+32) += P; float4 along n ----
    for (int it = 0; it < 4; ++it) {
        const int idx = t + it * 256;          // 0..1023
        const int o = idx >> 3, nq = idx & 7;
        float* op = Out + (size_t)o * N_NODES + n0 + nq * 4;
        float4 cur = *(const float4*)op;
        cur.x += P[PSWZ(nq * 4 + 0, o)];
        cur.y += P[PSWZ(nq * 4 + 1, o)];
        cur.z += P[PSWZ(nq * 4 + 2, o)];
        cur.w += P[PSWZ(nq * 4 + 3, o)];
        *(float4*)op = cur;
    }
}

// ---------------------------------------------------------------------------
// Legacy fused kernel (audited) -- fallback if workspace too small.
// ---------------------------------------------------------------------------
__global__ __launch_bounds__(256, 2) void k_fused_legacy(
    const float* __restrict__ X,
    const int*   __restrict__ adj,
    const float* __restrict__ W1,
    const float* __restrict__ B1,
    const float* __restrict__ W2,
    const float* __restrict__ B2,
    float*       __restrict__ Out)
{
    __shared__ __align__(16) float Xs[CH * XS_STRIDE];
    __shared__ __align__(16) float As[CH * XS_STRIDE];
    __shared__ int adjS[64 * K_NEIGH];

    const int t  = threadIdx.x;
    const int n0 = blockIdx.x * 64;
    const int V  = (N_NODES - n0 < 64) ? (N_NODES - n0) : 64;

    {
        const int base  = n0 * K_NEIGH;
        const int valid = V * K_NEIGH;
        for (int idx = t; idx < 64 * K_NEIGH; idx += 256)
            adjS[idx] = (idx < valid) ? adj[base + idx] : 0;
    }
    for (int it = 0; it < 32; ++it) {
        const int idx = t + it * 256;
        const int n = idx & 63, c = idx >> 6;
        Xs[c * XS_STRIDE + n] =
            (n < V) ? X[(size_t)c * N_NODES + n0 + n] : 0.0f;
    }
    __syncthreads();

    {
        const int n_l = t & 63, q = t >> 6;
        int js[K_NEIGH];
#pragma unroll
        for (int k = 0; k < K_NEIGH; ++k) js[k] = adjS[n_l * K_NEIGH + k];
        if (n_l < V) {
            for (int cc = 0; cc < 32; ++cc) {
                const int c = q * 32 + cc;
                const float* xc = X + (size_t)c * N_NODES;
                float s = 0.0f;
#pragma unroll
                for (int k = 0; k < K_NEIGH; ++k) s += xc[js[k]];
                As[c * XS_STRIDE + n_l] = s * 0.0625f;
            }
        } else {
            for (int cc = 0; cc < 32; ++cc)
                As[(q * 32 + cc) * XS_STRIDE + n_l] = 0.0f;
        }
    }
    __syncthreads();

    const int ng = t & 7, og = t >> 3;
    float acc[4][8];
#pragma unroll
    for (int i = 0; i < 4; ++i)
#pragma unroll
        for (int j = 0; j < 8; ++j) acc[i][j] = 0.0f;

    const float* w1p = W1 + (og * 4) * CH;
    const float* w2p = W2 + (og * 4) * CH;
    for (int c = 0; c < CH; ++c) {
        float xv[8], av[8], w1v[4], w2v[4];
        *(float4*)&xv[0] = *(const float4*)&Xs[c * XS_STRIDE + ng * 8];
        *(float4*)&xv[4] = *(const float4*)&Xs[c * XS_STRIDE + ng * 8 + 4];
        *(float4*)&av[0] = *(const float4*)&As[c * XS_STRIDE + ng * 8];
        *(float4*)&av[4] = *(const float4*)&As[c * XS_STRIDE + ng * 8 + 4];
#pragma unroll
        for (int i = 0; i < 4; ++i) {
            w1v[i] = w1p[i * CH + c];
            w2v[i] = w2p[i * CH + c];
        }
#pragma unroll
        for (int i = 0; i < 4; ++i)
#pragma unroll
            for (int j = 0; j < 8; ++j)
                acc[i][j] += w1v[i] * xv[j] + w2v[i] * av[j];
    }

    __syncthreads();
    float* Zt = Xs;
#pragma unroll
    for (int i = 0; i < 4; ++i) {
        *(float4*)&Zt[(og * 4 + i) * XS_STRIDE + ng * 8]     = *(float4*)&acc[i][0];
        *(float4*)&Zt[(og * 4 + i) * XS_STRIDE + ng * 8 + 4] = *(float4*)&acc[i][4];
    }
    __syncthreads();
    for (int it = 0; it < 32; ++it) {
        const int idx = t + it * 256;
        const int n = idx & 63, o = idx >> 6;
        if (n < V) {
            Out[(size_t)o * N_NODES + n0 + n] =
                Zt[o * XS_STRIDE + n] + B1[o] + B2[o];
        }
    }
}

extern "C" void kernel_launch(void* const* d_in, const int* in_sizes, int n_in,
                              void* d_out, int out_size, void* d_ws, size_t ws_size,
                              hipStream_t stream) {
    const float* X   = (const float*)d_in[0];
    const int*   adj = (const int*)d_in[1];
    const float* W1  = (const float*)d_in[2];
    const float* B1  = (const float*)d_in[3];
    const float* W2  = (const float*)d_in[4];
    const float* B2  = (const float*)d_in[5];
    float* Out = (float*)d_out;

    const size_t yt_elems = (size_t)N_NODES * CH;           // 12.8 M
    const size_t w_elems  = (size_t)CH * CH;                // 16384
    const size_t need = (yt_elems + 4 * w_elems) * sizeof(uint16_t);  // ~25.7 MB

    if (ws_size >= need) {
        uint16_t* Yt  = (uint16_t*)d_ws;
        uint16_t* W1h = Yt + yt_elems;
        uint16_t* W1l = W1h + w_elems;
        uint16_t* W2h = W1l + w_elems;
        uint16_t* W2l = W2h + w_elems;
        k_wcvt2<<<(2 * CH * CH + 255) / 256, 256, 0, stream>>>(
            W1, W2, W1h, W1l, W2h, W2l);
        const int nb1 = (N_NODES + 63) / 64;   // 1563
        k_dual<<<nb1, 256, 0, stream>>>(X, W1h, W1l, W2h, W2l, B1, B2, Yt, Out);
        const int nb2 = N_NODES / TN;          // 3125
        k_gather<<<nb2, 256, 0, stream>>>(adj, Yt, Out);
    } else {
        const int nblocks = (N_NODES + 63) / 64;
        k_fused_legacy<<<nblocks, 256, 0, stream>>>(X, adj, W1, B1, W2, B2, Out);
    }
}

// Round 12
// 237.670 us; speedup vs baseline: 1.1352x; 1.1352x over previous
//
#include <hip/hip_runtime.h>
#include <stdint.h>

#define N_NODES 100000
#define CH 128
#define K_NEIGH 16
#define TN 32          // k_gather node tile: 100000/32 = 3125 exact
#define XS_STRIDE 68   // legacy kernel only
#define PS 132         // pivot stride (node-major [n][o])

#define PSWZ(n, o) ((n) * PS + ((o) ^ ((((n) >> 3) & 3) << 3)))

// ============================================================================
// Round 20. r11 post-mortem: (a) 16-lane dwordx4 gather regressed 88->123
// (FETCH 240->296MB, 4 random rows/instr) -> exact r10 revert; (b) top-5 is
// globally sorted => k_dual has ALWAYS been < the top rows (<88us in r10);
// the "missing" ~50us/iter is launch/graph overhead + the extra k_wcvt
// launches. So: cut launches. W -> bf16 hi/lo conversion moves IN-REGISTER
// into k_dual's A-frag loads (f32 W loaded directly; ~770 VALU instr/thread
// amortized). 2 launches/iter total; workspace = Yt only.
// ============================================================================

typedef short bf8v __attribute__((ext_vector_type(8)));   // 8 bf16 = 4 VGPR
typedef float f32x4 __attribute__((ext_vector_type(4)));

__device__ __forceinline__ uint32_t pack_bf16x2(float a, float b) {
    union { float f; uint32_t u; } ua, ub;
    ua.f = a; ub.f = b;
    const uint32_t ra = (ua.u + 0x7fffu + ((ua.u >> 16) & 1u)) >> 16;
    const uint32_t rb = (ub.u + 0x7fffu + ((ub.u >> 16) & 1u)) >> 16;
    return ra | (rb << 16);
}
__device__ __forceinline__ uint16_t bf16_rne(float f) {
    union { float f; uint32_t u; } c; c.f = f;
    return (uint16_t)((c.u + 0x7fffu + ((c.u >> 16) & 1u)) >> 16);
}
__device__ __forceinline__ float bf16_tof(uint16_t h) {
    union { uint32_t u; float f; } c; c.u = ((uint32_t)h) << 16; return c.f;
}
__device__ __forceinline__ float bf16_lo(uint32_t u) {
    union { uint32_t u; float f; } c; c.u = u << 16; return c.f;
}
__device__ __forceinline__ float bf16_hi(uint32_t u) {
    union { uint32_t u; float f; } c; c.u = u & 0xffff0000u; return c.f;
}

// Load 8 consecutive f32 and split into bf16 hi/lo fragments (in-register).
__device__ __forceinline__ void cvt8(const float* __restrict__ p,
                                     bf8v& hv, bf8v& lv) {
    const float4 a = *(const float4*)p;
    const float4 b = *(const float4*)(p + 4);
    const float f[8] = {a.x, a.y, a.z, a.w, b.x, b.y, b.z, b.w};
#pragma unroll
    for (int i = 0; i < 8; ++i) {
        const uint16_t h = bf16_rne(f[i]);
        hv[i] = (short)h;
        lv[i] = (short)bf16_rne(f[i] - bf16_tof(h));
    }
}

// ---------------------------------------------------------------------------
// Kernel 1: k_dual. 64-node tile, 4 waves; wave w owns o in [32w, 32w+32).
//   Out[o][n] = D1 + B1[o] + B2[o],  D1 = (W1h+W1l)@Xh + W1h@Xl
//   Yt[n][o]  = bf16(D2),            D2 = (W2h+W2l)@Xh
// W converted f32 -> bf16 hi/lo in-register at A-frag load (no pre-kernel).
// ---------------------------------------------------------------------------
__global__ __launch_bounds__(256, 2) void k_dual(
    const float* __restrict__ X,    // [C][N] f32
    const float* __restrict__ W1,   // [o][c] f32
    const float* __restrict__ W2,   // [o][c] f32
    const float* __restrict__ B1,
    const float* __restrict__ B2,
    uint16_t*    __restrict__ Yt,   // [N][CH] bf16 (workspace)
    float*       __restrict__ Out)  // [O][N] f32
{
    __shared__ __align__(16) uint16_t XsH[64 * 128];  // 16 KB
    __shared__ __align__(16) uint16_t XsL[64 * 128];  // 16 KB

    const int t  = threadIdx.x;
    const int n0 = blockIdx.x * 64;
    const int V  = (N_NODES - n0 < 64) ? (N_NODES - n0) : 64;

    // ---- stage X (r10 form): f32 loads, hi/lo bf16, transposed swizzled ----
    for (int it = 0; it < 8; ++it) {
        const int idx = t + it * 256;          // 0..2047
        const int nq = idx & 15, c = idx >> 4;
        float4 v = make_float4(0.f, 0.f, 0.f, 0.f);
        if (nq * 4 < V)
            v = *(const float4*)&X[(size_t)c * N_NODES + n0 + nq * 4];
        const float vv0 = v.x, vv1 = v.y, vv2 = v.z, vv3 = v.w;
#pragma unroll
        for (int s = 0; s < 4; ++s) {
            const float f = (s == 0) ? vv0 : (s == 1) ? vv1 : (s == 2) ? vv2 : vv3;
            const int n = nq * 4 + s;
            const int byi = (n << 8) + (((c * 2)) ^ ((n & 7) << 4));
            const uint16_t h = bf16_rne(f);
            XsH[byi >> 1] = h;
            XsL[byi >> 1] = bf16_rne(f - bf16_tof(h));
        }
    }
    __syncthreads();

    const int l = t & 63;
    const int w = t >> 6;                 // wave id 0..3
    const int ar = l & 15;                // A row within 16-tile
    const int ac = (l >> 4) * 8;          // A k-offset

    f32x4 d1[2][4], d2[2][4];
#pragma unroll
    for (int ot = 0; ot < 2; ++ot)
#pragma unroll
        for (int nt = 0; nt < 4; ++nt) {
            d1[ot][nt] = (f32x4){0.f, 0.f, 0.f, 0.f};
            d2[ot][nt] = (f32x4){0.f, 0.f, 0.f, 0.f};
        }

#pragma unroll
    for (int ks = 0; ks < 4; ++ks) {
        // A-frags for this ks: load f32 W, convert hi/lo in-register.
        bf8v a1h[2], a1l[2], a2h[2], a2l[2];
#pragma unroll
        for (int ot = 0; ot < 2; ++ot) {
            const size_t off = (size_t)(w * 32 + ot * 16 + ar) * CH + ks * 32 + ac;
            cvt8(&W1[off], a1h[ot], a1l[ot]);
            cvt8(&W2[off], a2h[ot], a2l[ot]);
        }
#pragma unroll
        for (int nt = 0; nt < 4; ++nt) {
            const int n  = nt * 16 + (l & 15);
            const int byi = (n << 8) + ((ks * 64 + ((l >> 4) * 16)) ^ ((n & 7) << 4));
            const bf8v bh = *(const bf8v*)((const char*)XsH + byi);
            const bf8v bl = *(const bf8v*)((const char*)XsL + byi);
#pragma unroll
            for (int ot = 0; ot < 2; ++ot) {
                d1[ot][nt] = __builtin_amdgcn_mfma_f32_16x16x32_bf16(
                    a1h[ot], bh, d1[ot][nt], 0, 0, 0);
                d1[ot][nt] = __builtin_amdgcn_mfma_f32_16x16x32_bf16(
                    a1l[ot], bh, d1[ot][nt], 0, 0, 0);
                d1[ot][nt] = __builtin_amdgcn_mfma_f32_16x16x32_bf16(
                    a1h[ot], bl, d1[ot][nt], 0, 0, 0);
                d2[ot][nt] = __builtin_amdgcn_mfma_f32_16x16x32_bf16(
                    a2h[ot], bh, d2[ot][nt], 0, 0, 0);
                d2[ot][nt] = __builtin_amdgcn_mfma_f32_16x16x32_bf16(
                    a2l[ot], bh, d2[ot][nt], 0, 0, 0);
            }
        }
    }

    // ---- Out stores: D1 + biases ----
#pragma unroll
    for (int ot = 0; ot < 2; ++ot) {
        const int ob = w * 32 + ot * 16 + (l >> 4) * 4;
        const float b0 = B1[ob + 0] + B2[ob + 0];
        const float b1 = B1[ob + 1] + B2[ob + 1];
        const float b2 = B1[ob + 2] + B2[ob + 2];
        const float b3 = B1[ob + 3] + B2[ob + 3];
#pragma unroll
        for (int nt = 0; nt < 4; ++nt) {
            const int n = nt * 16 + (l & 15);
            if (n < V) {
                float* op = Out + (size_t)ob * N_NODES + n0 + n;
                op[0]                   = d1[ot][nt][0] + b0;
                op[(size_t)N_NODES]     = d1[ot][nt][1] + b1;
                op[(size_t)N_NODES * 2] = d1[ot][nt][2] + b2;
                op[(size_t)N_NODES * 3] = d1[ot][nt][3] + b3;
            }
        }
    }

    // ---- Yt stores: bf16(D2), 8B per (ot,nt) ----
#pragma unroll
    for (int ot = 0; ot < 2; ++ot)
#pragma unroll
        for (int nt = 0; nt < 4; ++nt) {
            const int n = nt * 16 + (l & 15);
            if (n < V) {
                const int o4 = w * 32 + ot * 16 + (l >> 4) * 4;
                uint2 pv;
                pv.x = pack_bf16x2(d2[ot][nt][0], d2[ot][nt][1]);
                pv.y = pack_bf16x2(d2[ot][nt][2], d2[ot][nt][3]);
                *(uint2*)&Yt[(size_t)(n0 + n) * CH + o4] = pv;
            }
        }
}

// ---------------------------------------------------------------------------
// Kernel 2: k_gather (exact r10 revert, 88us audited).
// Out[o][n] += mean_k bf16(Yt)[adj[n][k]][o]. 32-node tiles, 8 blocks/CU.
// ---------------------------------------------------------------------------
__global__ __launch_bounds__(256, 8) void k_gather(
    const int*      __restrict__ adj,  // [N][K] int32
    const uint16_t* __restrict__ Yt,   // [N][CH] bf16
    float*          __restrict__ Out)  // [O][N] f32
{
    __shared__ __align__(16) float P[TN * PS];        // 16.9 KB
    __shared__ __align__(16) int adjS[TN * K_NEIGH];  // 2 KB

    const int t  = threadIdx.x;
    const int n0 = blockIdx.x * TN;   // exact tiles

    if (t < 128)
        *(int4*)&adjS[t * 4] = *(const int4*)&adj[(size_t)n0 * K_NEIGH + t * 4];
    __syncthreads();

    // ---- gather-mean: 8 groups of 32 lanes; lane owns 4 channels ----
    {
        const int l4 = (t & 31) * 4;
        const int g  = t >> 5;
        for (int itp = 0; itp < 4; ++itp) {
            const int n = itp * 8 + g;
            int js[K_NEIGH];
#pragma unroll
            for (int k = 0; k < K_NEIGH; ++k) js[k] = adjS[n * K_NEIGH + k];
            float4 a0 = make_float4(0.f, 0.f, 0.f, 0.f);
            float4 a1 = make_float4(0.f, 0.f, 0.f, 0.f);
#pragma unroll
            for (int k = 0; k < K_NEIGH; k += 2) {
                const uint2 v0 = *(const uint2*)&Yt[(size_t)js[k]     * CH + l4];
                const uint2 v1 = *(const uint2*)&Yt[(size_t)js[k + 1] * CH + l4];
                a0.x += bf16_lo(v0.x); a0.y += bf16_hi(v0.x);
                a0.z += bf16_lo(v0.y); a0.w += bf16_hi(v0.y);
                a1.x += bf16_lo(v1.x); a1.y += bf16_hi(v1.x);
                a1.z += bf16_lo(v1.y); a1.w += bf16_hi(v1.y);
            }
            float4 s;
            s.x = (a0.x + a1.x) * 0.0625f;
            s.y = (a0.y + a1.y) * 0.0625f;
            s.z = (a0.z + a1.z) * 0.0625f;
            s.w = (a0.w + a1.w) * 0.0625f;
            *(float4*)&P[PSWZ(n, l4)] = s;   // contiguous 128B/group
        }
    }
    __syncthreads();

    // ---- RMW epilogue: Out[o][n0..n0+32) += P; float4 along n ----
    for (int it = 0; it < 4; ++it) {
        const int idx = t + it * 256;          // 0..1023
        const int o = idx >> 3, nq = idx & 7;
        float* op = Out + (size_t)o * N_NODES + n0 + nq * 4;
        float4 cur = *(const float4*)op;
        cur.x += P[PSWZ(nq * 4 + 0, o)];
        cur.y += P[PSWZ(nq * 4 + 1, o)];
        cur.z += P[PSWZ(nq * 4 + 2, o)];
        cur.w += P[PSWZ(nq * 4 + 3, o)];
        *(float4*)op = cur;
    }
}

// ---------------------------------------------------------------------------
// Legacy fused kernel (audited) -- fallback if workspace too small.
// ---------------------------------------------------------------------------
__global__ __launch_bounds__(256, 2) void k_fused_legacy(
    const float* __restrict__ X,
    const int*   __restrict__ adj,
    const float* __restrict__ W1,
    const float* __restrict__ B1,
    const float* __restrict__ W2,
    const float* __restrict__ B2,
    float*       __restrict__ Out)
{
    __shared__ __align__(16) float Xs[CH * XS_STRIDE];
    __shared__ __align__(16) float As[CH * XS_STRIDE];
    __shared__ int adjS[64 * K_NEIGH];

    const int t  = threadIdx.x;
    const int n0 = blockIdx.x * 64;
    const int V  = (N_NODES - n0 < 64) ? (N_NODES - n0) : 64;

    {
        const int base  = n0 * K_NEIGH;
        const int valid = V * K_NEIGH;
        for (int idx = t; idx < 64 * K_NEIGH; idx += 256)
            adjS[idx] = (idx < valid) ? adj[base + idx] : 0;
    }
    for (int it = 0; it < 32; ++it) {
        const int idx = t + it * 256;
        const int n = idx & 63, c = idx >> 6;
        Xs[c * XS_STRIDE + n] =
            (n < V) ? X[(size_t)c * N_NODES + n0 + n] : 0.0f;
    }
    __syncthreads();

    {
        const int n_l = t & 63, q = t >> 6;
        int js[K_NEIGH];
#pragma unroll
        for (int k = 0; k < K_NEIGH; ++k) js[k] = adjS[n_l * K_NEIGH + k];
        if (n_l < V) {
            for (int cc = 0; cc < 32; ++cc) {
                const int c = q * 32 + cc;
                const float* xc = X + (size_t)c * N_NODES;
                float s = 0.0f;
#pragma unroll
                for (int k = 0; k < K_NEIGH; ++k) s += xc[js[k]];
                As[c * XS_STRIDE + n_l] = s * 0.0625f;
            }
        } else {
            for (int cc = 0; cc < 32; ++cc)
                As[(q * 32 + cc) * XS_STRIDE + n_l] = 0.0f;
        }
    }
    __syncthreads();

    const int ng = t & 7, og = t >> 3;
    float acc[4][8];
#pragma unroll
    for (int i = 0; i < 4; ++i)
#pragma unroll
        for (int j = 0; j < 8; ++j) acc[i][j] = 0.0f;

    const float* w1p = W1 + (og * 4) * CH;
    const float* w2p = W2 + (og * 4) * CH;
    for (int c = 0; c < CH; ++c) {
        float xv[8], av[8], w1v[4], w2v[4];
        *(float4*)&xv[0] = *(const float4*)&Xs[c * XS_STRIDE + ng * 8];
        *(float4*)&xv[4] = *(const float4*)&Xs[c * XS_STRIDE + ng * 8 + 4];
        *(float4*)&av[0] = *(const float4*)&As[c * XS_STRIDE + ng * 8];
        *(float4*)&av[4] = *(const float4*)&As[c * XS_STRIDE + ng * 8 + 4];
#pragma unroll
        for (int i = 0; i < 4; ++i) {
            w1v[i] = w1p[i * CH + c];
            w2v[i] = w2p[i * CH + c];
        }
#pragma unroll
        for (int i = 0; i < 4; ++i)
#pragma unroll
            for (int j = 0; j < 8; ++j)
                acc[i][j] += w1v[i] * xv[j] + w2v[i] * av[j];
    }

    __syncthreads();
    float* Zt = Xs;
#pragma unroll
    for (int i = 0; i < 4; ++i) {
        *(float4*)&Zt[(og * 4 + i) * XS_STRIDE + ng * 8]     = *(float4*)&acc[i][0];
        *(float4*)&Zt[(og * 4 + i) * XS_STRIDE + ng * 8 + 4] = *(float4*)&acc[i][4];
    }
    __syncthreads();
    for (int it = 0; it < 32; ++it) {
        const int idx = t + it * 256;
        const int n = idx & 63, o = idx >> 6;
        if (n < V) {
            Out[(size_t)o * N_NODES + n0 + n] =
                Zt[o * XS_STRIDE + n] + B1[o] + B2[o];
        }
    }
}

extern "C" void kernel_launch(void* const* d_in, const int* in_sizes, int n_in,
                              void* d_out, int out_size, void* d_ws, size_t ws_size,
                              hipStream_t stream) {
    const float* X   = (const float*)d_in[0];
    const int*   adj = (const int*)d_in[1];
    const float* W1  = (const float*)d_in[2];
    const float* B1  = (const float*)d_in[3];
    const float* W2  = (const float*)d_in[4];
    const float* B2  = (const float*)d_in[5];
    float* Out = (float*)d_out;

    const size_t yt_bytes = (size_t)N_NODES * CH * sizeof(uint16_t);  // 25.6 MB

    if (ws_size >= yt_bytes) {
        uint16_t* Yt = (uint16_t*)d_ws;
        const int nb1 = (N_NODES + 63) / 64;   // 1563
        k_dual<<<nb1, 256, 0, stream>>>(X, W1, W2, B1, B2, Yt, Out);
        const int nb2 = N_NODES / TN;          // 3125
        k_gather<<<nb2, 256, 0, stream>>>(adj, Yt, Out);
    } else {
        const int nblocks = (N_NODES + 63) / 64;
        k_fused_legacy<<<nblocks, 256, 0, stream>>>(X, adj, W1, B1, W2, B2, Out);
    }
}

// Round 13
// 229.667 us; speedup vs baseline: 1.1747x; 1.0348x over previous
//
#include <hip/hip_runtime.h>
#include <stdint.h>

#define N_NODES 100000
#define CH 128
#define K_NEIGH 16
#define TN 32          // fused tile: 100000/32 = 3125 exact, no tails
#define XS_STRIDE 68   // X f32 staging stride (k_xt + legacy)

// ============================================================================
// Round 21. r12 ledger: k_dual <= 88us (never in top-5), k_gather 88us AT the
// mixed-memory roofline (522MB logical / 88us = 5.9TB/s), yet total = 237.7
// => ~60us fixed cost in the dual->gather boundary; both kernels near their
// own floors. Shape change:
//  * k_xt: X -> XtH/XtL [N][C] bf16 (hi/lo). Pure transpose+split, ~25us.
//  * k_fused2: per 32-node tile: gather-mean from XtH (r12-audited loop,
//    same traffic) -> agg bf16 in LDS; THEN both GEMMs (d1 from global Xt
//    hi/lo frags, 3-MFMA; d2 from LDS aggH, 2-MFMA) -> Out = d1+d2+b ONCE
//    (no RMW re-read). GEMM hides under gather latency instead of being a
//    serial 88us stage. 3125 exact tiles: zero guards.
// ============================================================================

typedef short bf8v __attribute__((ext_vector_type(8)));   // 8 bf16 = 4 VGPR
typedef float f32x4 __attribute__((ext_vector_type(4)));

__device__ __forceinline__ uint32_t pack_bf16x2(float a, float b) {
    union { float f; uint32_t u; } ua, ub;
    ua.f = a; ub.f = b;
    const uint32_t ra = (ua.u + 0x7fffu + ((ua.u >> 16) & 1u)) >> 16;
    const uint32_t rb = (ub.u + 0x7fffu + ((ub.u >> 16) & 1u)) >> 16;
    return ra | (rb << 16);
}
__device__ __forceinline__ uint16_t bf16_rne(float f) {
    union { float f; uint32_t u; } c; c.f = f;
    return (uint16_t)((c.u + 0x7fffu + ((c.u >> 16) & 1u)) >> 16);
}
__device__ __forceinline__ float bf16_tof(uint16_t h) {
    union { uint32_t u; float f; } c; c.u = ((uint32_t)h) << 16; return c.f;
}
__device__ __forceinline__ float bf16_lo(uint32_t u) {
    union { uint32_t u; float f; } c; c.u = u << 16; return c.f;
}
__device__ __forceinline__ float bf16_hi(uint32_t u) {
    union { uint32_t u; float f; } c; c.u = u & 0xffff0000u; return c.f;
}

// Load 8 consecutive f32, split into bf16 hi/lo fragments (in-register).
__device__ __forceinline__ void cvt8(const float* __restrict__ p,
                                     bf8v& hv, bf8v& lv) {
    const float4 a = *(const float4*)p;
    const float4 b = *(const float4*)(p + 4);
    const float f[8] = {a.x, a.y, a.z, a.w, b.x, b.y, b.z, b.w};
#pragma unroll
    for (int i = 0; i < 8; ++i) {
        const uint16_t h = bf16_rne(f[i]);
        hv[i] = (short)h;
        lv[i] = (short)bf16_rne(f[i] - bf16_tof(h));
    }
}

// ---------------------------------------------------------------------------
// Kernel 1: k_xt. X[C][N] f32 -> XtH/XtL [N][CH] bf16 (hi/lo split).
// 64-node tiles (1563 blocks, guarded tail), 34.8KB LDS, 4 blocks/CU.
// ---------------------------------------------------------------------------
__global__ __launch_bounds__(256, 4) void k_xt(
    const float* __restrict__ X,     // [C][N] f32
    uint16_t*    __restrict__ XtH,   // [N][CH] bf16 hi
    uint16_t*    __restrict__ XtL)   // [N][CH] bf16 lo
{
    __shared__ __align__(16) float Xs[CH * XS_STRIDE];  // 34.8 KB

    const int t  = threadIdx.x;
    const int n0 = blockIdx.x * 64;
    const int V  = (N_NODES - n0 < 64) ? (N_NODES - n0) : 64;

    // stage X tile [c][n] as float4 (guarded; r3-audited pattern)
    for (int it = 0; it < 8; ++it) {
        const int idx = t + it * 256;          // 0..2047
        const int nq = idx & 15, c = idx >> 4;
        float4 v = make_float4(0.f, 0.f, 0.f, 0.f);
        if (nq * 4 < V)
            v = *(const float4*)&X[(size_t)c * N_NODES + n0 + nq * 4];
        *(float4*)&Xs[c * XS_STRIDE + nq * 4] = v;
    }
    __syncthreads();

    // write-out: thread owns node n = t&63, channel half = t>>6 (32 ch).
    // LDS reads 2-way bank (free); stores 16B x 4 per plane, rows 256B.
    const int n = t & 63, half = t >> 6;
    if (n < V) {
        uint32_t ph[16], pl[16];
#pragma unroll
        for (int cc = 0; cc < 32; cc += 2) {
            const float f0 = Xs[(half * 32 + cc) * XS_STRIDE + n];
            const float f1 = Xs[(half * 32 + cc + 1) * XS_STRIDE + n];
            const uint16_t h0 = bf16_rne(f0), h1 = bf16_rne(f1);
            ph[cc >> 1] = (uint32_t)h0 | ((uint32_t)h1 << 16);
            const uint16_t l0 = bf16_rne(f0 - bf16_tof(h0));
            const uint16_t l1 = bf16_rne(f1 - bf16_tof(h1));
            pl[cc >> 1] = (uint32_t)l0 | ((uint32_t)l1 << 16);
        }
        uint16_t* dh = &XtH[(size_t)(n0 + n) * CH + half * 32];
        uint16_t* dl = &XtL[(size_t)(n0 + n) * CH + half * 32];
#pragma unroll
        for (int j = 0; j < 4; ++j) {
            *(uint4*)&dh[j * 8] = *(uint4*)&ph[j * 4];
            *(uint4*)&dl[j * 8] = *(uint4*)&pl[j * 4];
        }
    }
}

// ---------------------------------------------------------------------------
// Kernel 2: k_fused2. Per 32-node tile (3125 blocks, exact):
//   agg[n][c] = mean_k XtH[adj[n][k]][c]      (gather, r12-audited loop)
//   Out[o][n] = W1@X (3-MFMA hi/lo from global Xt) + W2@agg (2-MFMA from LDS)
//             + B1[o] + B2[o]
// LDS: AggH 8KB (byi-swizzled) + adjS 2KB = 10KB. (256,4) -> 16 waves/CU.
// byi(n,c) = (n<<8) + ((2c) ^ ((n&7)<<4))  -- same swizzle family as r12.
// ---------------------------------------------------------------------------
__global__ __launch_bounds__(256, 4) void k_fused2(
    const int*      __restrict__ adj,  // [N][K] int32
    const uint16_t* __restrict__ XtH,  // [N][CH] bf16 hi
    const uint16_t* __restrict__ XtL,  // [N][CH] bf16 lo
    const float*    __restrict__ W1,   // [o][c] f32
    const float*    __restrict__ W2,   // [o][c] f32
    const float*    __restrict__ B1,
    const float*    __restrict__ B2,
    float*          __restrict__ Out)  // [O][N] f32
{
    __shared__ __align__(16) uint16_t AggH[TN * CH];   // 8 KB
    __shared__ __align__(16) int adjS[TN * K_NEIGH];   // 2 KB

    const int t  = threadIdx.x;
    const int n0 = blockIdx.x * TN;    // exact tiles, no guards anywhere

    // ---- stage adj: 512 ints = 128 int4 ----
    if (t < 128)
        *(int4*)&adjS[t * 4] = *(const int4*)&adj[(size_t)n0 * K_NEIGH + t * 4];
    __syncthreads();

    // ---- gather-mean from XtH -> AggH (bf16, byi layout) ----
    // 8 groups x 32 lanes; group g: nodes {g, 8+g, 16+g, 24+g}; lane owns
    // channels 4l..4l+3 (uint2 8B). Identical traffic/pattern to r12 k_gather.
    {
        const int lq = t & 31;
        const int l4 = lq * 4;
        const int g  = t >> 5;
        for (int itp = 0; itp < 4; ++itp) {
            const int n = itp * 8 + g;
            int js[K_NEIGH];
#pragma unroll
            for (int k = 0; k < K_NEIGH; ++k) js[k] = adjS[n * K_NEIGH + k];
            float4 a0 = make_float4(0.f, 0.f, 0.f, 0.f);
            float4 a1 = make_float4(0.f, 0.f, 0.f, 0.f);
#pragma unroll
            for (int k = 0; k < K_NEIGH; k += 2) {
                const uint2 v0 = *(const uint2*)&XtH[(size_t)js[k]     * CH + l4];
                const uint2 v1 = *(const uint2*)&XtH[(size_t)js[k + 1] * CH + l4];
                a0.x += bf16_lo(v0.x); a0.y += bf16_hi(v0.x);
                a0.z += bf16_lo(v0.y); a0.w += bf16_hi(v0.y);
                a1.x += bf16_lo(v1.x); a1.y += bf16_hi(v1.x);
                a1.z += bf16_lo(v1.y); a1.w += bf16_hi(v1.y);
            }
            const float sx = (a0.x + a1.x) * 0.0625f;
            const float sy = (a0.y + a1.y) * 0.0625f;
            const float sz = (a0.z + a1.z) * 0.0625f;
            const float sw = (a0.w + a1.w) * 0.0625f;
            // pack 4 bf16 -> 8B slot at byi(n, l4); 8-aligned (key bits 4..6).
            uint2 pv;
            pv.x = pack_bf16x2(sx, sy);
            pv.y = pack_bf16x2(sz, sw);
            const int byi = (n << 8) + ((8 * lq) ^ ((n & 7) << 4));
            *(uint2*)((char*)AggH + byi) = pv;
        }
    }
    __syncthreads();

    // ---- dual GEMM: wave w owns o in [32w,32w+32); nt over 2 n-tiles ----
    const int l = t & 63;
    const int w = t >> 6;
    const int ar = l & 15;                // A row within 16-tile
    const int ac = (l >> 4) * 8;          // A k-offset

    f32x4 d1[2][2], d2[2][2];             // [ot][nt]
#pragma unroll
    for (int ot = 0; ot < 2; ++ot)
#pragma unroll
        for (int nt = 0; nt < 2; ++nt) {
            d1[ot][nt] = (f32x4){0.f, 0.f, 0.f, 0.f};
            d2[ot][nt] = (f32x4){0.f, 0.f, 0.f, 0.f};
        }

#pragma unroll
    for (int ks = 0; ks < 4; ++ks) {
        // A-frags: f32 W -> hi/lo in-register (r12-proven cvt8)
        bf8v a1h[2], a1l[2], a2h[2], a2l[2];
#pragma unroll
        for (int ot = 0; ot < 2; ++ot) {
            const size_t off = (size_t)(w * 32 + ot * 16 + ar) * CH + ks * 32 + ac;
            cvt8(&W1[off], a1h[ot], a1l[ot]);
            cvt8(&W2[off], a2h[ot], a2l[ot]);
        }
#pragma unroll
        for (int nt = 0; nt < 2; ++nt) {
            const int n = nt * 16 + (l & 15);       // 0..31
            // d1 B-frags straight from global Xt rows (16B/lane, coalesced)
            const size_t gidx = (size_t)(n0 + n) * CH + ks * 32 + ac;
            const bf8v bh = *(const bf8v*)&XtH[gidx];
            const bf8v bl = *(const bf8v*)&XtL[gidx];
            // d2 B-frag from LDS AggH (byi-swizzled)
            const int byi = (n << 8) + ((ks * 64 + ((l >> 4) * 16)) ^ ((n & 7) << 4));
            const bf8v gh = *(const bf8v*)((const char*)AggH + byi);
#pragma unroll
            for (int ot = 0; ot < 2; ++ot) {
                d1[ot][nt] = __builtin_amdgcn_mfma_f32_16x16x32_bf16(
                    a1h[ot], bh, d1[ot][nt], 0, 0, 0);
                d1[ot][nt] = __builtin_amdgcn_mfma_f32_16x16x32_bf16(
                    a1l[ot], bh, d1[ot][nt], 0, 0, 0);
                d1[ot][nt] = __builtin_amdgcn_mfma_f32_16x16x32_bf16(
                    a1h[ot], bl, d1[ot][nt], 0, 0, 0);
                d2[ot][nt] = __builtin_amdgcn_mfma_f32_16x16x32_bf16(
                    a2h[ot], gh, d2[ot][nt], 0, 0, 0);
                d2[ot][nt] = __builtin_amdgcn_mfma_f32_16x16x32_bf16(
                    a2l[ot], gh, d2[ot][nt], 0, 0, 0);
            }
        }
    }

    // ---- Out = d1 + d2 + biases; single write, no RMW ----
#pragma unroll
    for (int ot = 0; ot < 2; ++ot) {
        const int ob = w * 32 + ot * 16 + (l >> 4) * 4;
        const float b0 = B1[ob + 0] + B2[ob + 0];
        const float b1 = B1[ob + 1] + B2[ob + 1];
        const float b2 = B1[ob + 2] + B2[ob + 2];
        const float b3 = B1[ob + 3] + B2[ob + 3];
#pragma unroll
        for (int nt = 0; nt < 2; ++nt) {
            const int n = nt * 16 + (l & 15);
            float* op = Out + (size_t)ob * N_NODES + n0 + n;
            op[0]                   = d1[ot][nt][0] + d2[ot][nt][0] + b0;
            op[(size_t)N_NODES]     = d1[ot][nt][1] + d2[ot][nt][1] + b1;
            op[(size_t)N_NODES * 2] = d1[ot][nt][2] + d2[ot][nt][2] + b2;
            op[(size_t)N_NODES * 3] = d1[ot][nt][3] + d2[ot][nt][3] + b3;
        }
    }
}

// ---------------------------------------------------------------------------
// Legacy fused kernel (audited) -- fallback if workspace too small.
// ---------------------------------------------------------------------------
__global__ __launch_bounds__(256, 2) void k_fused_legacy(
    const float* __restrict__ X,
    const int*   __restrict__ adj,
    const float* __restrict__ W1,
    const float* __restrict__ B1,
    const float* __restrict__ W2,
    const float* __restrict__ B2,
    float*       __restrict__ Out)
{
    __shared__ __align__(16) float Xs[CH * XS_STRIDE];
    __shared__ __align__(16) float As[CH * XS_STRIDE];
    __shared__ int adjS[64 * K_NEIGH];

    const int t  = threadIdx.x;
    const int n0 = blockIdx.x * 64;
    const int V  = (N_NODES - n0 < 64) ? (N_NODES - n0) : 64;

    {
        const int base  = n0 * K_NEIGH;
        const int valid = V * K_NEIGH;
        for (int idx = t; idx < 64 * K_NEIGH; idx += 256)
            adjS[idx] = (idx < valid) ? adj[base + idx] : 0;
    }
    for (int it = 0; it < 32; ++it) {
        const int idx = t + it * 256;
        const int n = idx & 63, c = idx >> 6;
        Xs[c * XS_STRIDE + n] =
            (n < V) ? X[(size_t)c * N_NODES + n0 + n] : 0.0f;
    }
    __syncthreads();

    {
        const int n_l = t & 63, q = t >> 6;
        int js[K_NEIGH];
#pragma unroll
        for (int k = 0; k < K_NEIGH; ++k) js[k] = adjS[n_l * K_NEIGH + k];
        if (n_l < V) {
            for (int cc = 0; cc < 32; ++cc) {
                const int c = q * 32 + cc;
                const float* xc = X + (size_t)c * N_NODES;
                float s = 0.0f;
#pragma unroll
                for (int k = 0; k < K_NEIGH; ++k) s += xc[js[k]];
                As[c * XS_STRIDE + n_l] = s * 0.0625f;
            }
        } else {
            for (int cc = 0; cc < 32; ++cc)
                As[(q * 32 + cc) * XS_STRIDE + n_l] = 0.0f;
        }
    }
    __syncthreads();

    const int ng = t & 7, og = t >> 3;
    float acc[4][8];
#pragma unroll
    for (int i = 0; i < 4; ++i)
#pragma unroll
        for (int j = 0; j < 8; ++j) acc[i][j] = 0.0f;

    const float* w1p = W1 + (og * 4) * CH;
    const float* w2p = W2 + (og * 4) * CH;
    for (int c = 0; c < CH; ++c) {
        float xv[8], av[8], w1v[4], w2v[4];
        *(float4*)&xv[0] = *(const float4*)&Xs[c * XS_STRIDE + ng * 8];
        *(float4*)&xv[4] = *(const float4*)&Xs[c * XS_STRIDE + ng * 8 + 4];
        *(float4*)&av[0] = *(const float4*)&As[c * XS_STRIDE + ng * 8];
        *(float4*)&av[4] = *(const float4*)&As[c * XS_STRIDE + ng * 8 + 4];
#pragma unroll
        for (int i = 0; i < 4; ++i) {
            w1v[i] = w1p[i * CH + c];
            w2v[i] = w2p[i * CH + c];
        }
#pragma unroll
        for (int i = 0; i < 4; ++i)
#pragma unroll
            for (int j = 0; j < 8; ++j)
                acc[i][j] += w1v[i] * xv[j] + w2v[i] * av[j];
    }

    __syncthreads();
    float* Zt = Xs;
#pragma unroll
    for (int i = 0; i < 4; ++i) {
        *(float4*)&Zt[(og * 4 + i) * XS_STRIDE + ng * 8]     = *(float4*)&acc[i][0];
        *(float4*)&Zt[(og * 4 + i) * XS_STRIDE + ng * 8 + 4] = *(float4*)&acc[i][4];
    }
    __syncthreads();
    for (int it = 0; it < 32; ++it) {
        const int idx = t + it * 256;
        const int n = idx & 63, o = idx >> 6;
        if (n < V) {
            Out[(size_t)o * N_NODES + n0 + n] =
                Zt[o * XS_STRIDE + n] + B1[o] + B2[o];
        }
    }
}

extern "C" void kernel_launch(void* const* d_in, const int* in_sizes, int n_in,
                              void* d_out, int out_size, void* d_ws, size_t ws_size,
                              hipStream_t stream) {
    const float* X   = (const float*)d_in[0];
    const int*   adj = (const int*)d_in[1];
    const float* W1  = (const float*)d_in[2];
    const float* B1  = (const float*)d_in[3];
    const float* W2  = (const float*)d_in[4];
    const float* B2  = (const float*)d_in[5];
    float* Out = (float*)d_out;

    const size_t xt_elems = (size_t)N_NODES * CH;                 // 12.8 M
    const size_t need     = 2 * xt_elems * sizeof(uint16_t);      // 51.2 MB

    if (ws_size >= need) {
        uint16_t* XtH = (uint16_t*)d_ws;
        uint16_t* XtL = XtH + xt_elems;
        const int nb1 = (N_NODES + 63) / 64;   // 1563
        k_xt<<<nb1, 256, 0, stream>>>(X, XtH, XtL);
        const int nb2 = N_NODES / TN;          // 3125, exact
        k_fused2<<<nb2, 256, 0, stream>>>(adj, XtH, XtL, W1, W2, B1, B2, Out);
    } else {
        const int nblocks = (N_NODES + 63) / 64;
        k_fused_legacy<<<nblocks, 256, 0, stream>>>(X, adj, W1, B1, W2, B2, Out);
    }
}